// Round 2
// baseline (817.910 us; speedup 1.0000x reference)
//
#include <hip/hip_runtime.h>
#include <hip/hip_bf16.h>

typedef __hip_bfloat16 bf16;

#define B_ 2
#define T_ 1024
#define C_ 1024
#define H_ 16
#define N_ 64

using short8 = __attribute__((ext_vector_type(8))) short;
using f32x4 = __attribute__((ext_vector_type(4))) float;

__device__ __forceinline__ float us2f(unsigned short u) {
  return __uint_as_float(((unsigned int)u) << 16);
}
__device__ __forceinline__ float bs2f(short s) {
  return __uint_as_float(((unsigned int)(unsigned short)s) << 16);
}
__device__ __forceinline__ bf16 f2bf(float f) { return __float2bfloat16(f); }
__device__ __forceinline__ float sigmoidf_(float x) { return 1.0f / (1.0f + expf(-x)); }
__device__ __forceinline__ float softplusf_(float x) {
  return fmaxf(x, 0.0f) + log1pf(expf(-fabsf(x)));
}
// Full 16-lane-row sum, all lanes receive the result. Pure-VALU DPP:
// quad_perm xor1, xor2 give quad sums; row_ror:4 + row_ror:8 complete it.
__device__ __forceinline__ float qsum16(float x) {
  int a = __builtin_amdgcn_update_dpp(0, __float_as_int(x), 0xB1, 0xF, 0xF, true);
  x += __int_as_float(a);                       // quad_perm [1,0,3,2] (xor 1)
  int b = __builtin_amdgcn_update_dpp(0, __float_as_int(x), 0x4E, 0xF, 0xF, true);
  x += __int_as_float(b);                       // quad_perm [2,3,0,1] (xor 2)
  int c = __builtin_amdgcn_update_dpp(0, __float_as_int(x), 0x124, 0xF, 0xF, true);
  x += __int_as_float(c);                       // row_ror:4
  int d = __builtin_amdgcn_update_dpp(0, __float_as_int(x), 0x128, 0xF, 0xF, true);
  x += __int_as_float(d);                       // row_ror:8
  return x;
}

// ---------------- K0: fused weight fp32->bf16 conversion (big weights) ------
__global__ __launch_bounds__(256) void cvt_weights_kernel(
    const float* __restrict__ s0, const float* __restrict__ s1,
    const float* __restrict__ s2, const float* __restrict__ s3,
    const float* __restrict__ s4, const float* __restrict__ s5,
    const float* __restrict__ s6,
    bf16* __restrict__ d0, bf16* __restrict__ d1, bf16* __restrict__ d2,
    bf16* __restrict__ d3, bf16* __restrict__ d4, bf16* __restrict__ d5,
    bf16* __restrict__ d6) {
  long i4 = (long)blockIdx.x * 256 + threadIdx.x;
  const float* s; bf16* d; long off;
  if (i4 < 32768) { s = s0; d = d0; off = i4; }
  else if (i4 < 294912) { s = s1; d = d1; off = i4 - 32768; }
  else if (i4 < 327680) { s = s2; d = d2; off = i4 - 294912; }
  else if (i4 < 360448) { s = s3; d = d3; off = i4 - 327680; }
  else if (i4 < 622592) { s = s4; d = d4; off = i4 - 360448; }
  else if (i4 < 884736) { s = s5; d = d5; off = i4 - 622592; }
  else { s = s6; d = d6; off = i4 - 884736; }
  float4 v = *(const float4*)(s + off * 4);
  d[off * 4 + 0] = f2bf(v.x);
  d[off * 4 + 1] = f2bf(v.y);
  d[off * 4 + 2] = f2bf(v.z);
  d[off * 4 + 3] = f2bf(v.w);
}

// ---------------- K0b: pack small LoRA-1 weights to bf16 --------------------
__global__ __launch_bounds__(256) void cvt_small_kernel(
    const float* __restrict__ tkw1, const float* __restrict__ mkw1,
    const float* __restrict__ tdw1, const float* __restrict__ taw1,
    const float* __restrict__ maw1,
    bf16* __restrict__ wsk, bf16* __restrict__ wswa) {
  long i4 = (long)blockIdx.x * 256 + threadIdx.x;  // < 32768
  const float* s; bf16* d; long so, dof;
  if (i4 < 4096) { s = tkw1; so = i4; d = wsk; dof = i4; }
  else if (i4 < 8192) { s = mkw1; so = i4 - 4096; d = wsk; dof = i4; }
  else if (i4 < 24576) { s = tdw1; so = i4 - 8192; d = wswa; dof = i4 - 8192; }
  else if (i4 < 28672) { s = taw1; so = i4 - 24576; d = wswa; dof = i4 - 8192; }
  else { s = maw1; so = i4 - 28672; d = wswa; dof = i4 - 8192; }
  float4 v = *(const float4*)(s + so * 4);
  d[dof * 4 + 0] = f2bf(v.x);
  d[dof * 4 + 1] = f2bf(v.y);
  d[dof * 4 + 2] = f2bf(v.z);
  d[dof * 4 + 3] = f2bf(v.w);
}

// ---------------- K0c: LoRA-2 weights to bf16 -------------------------------
__global__ __launch_bounds__(256) void cvt_small2_kernel(
    const float* __restrict__ tmw2, const float* __restrict__ tdw2,
    const float* __restrict__ tkw2, const float* __restrict__ taw2,
    const float* __restrict__ maw2, const float* __restrict__ mkw2,
    bf16* __restrict__ tmw2b, bf16* __restrict__ tdw2b,
    bf16* __restrict__ tkw2b, bf16* __restrict__ taw2b,
    bf16* __restrict__ maw2b, bf16* __restrict__ mkw2b) {
  long i4 = (long)blockIdx.x * 256 + threadIdx.x;  // < 65536
  const float* s; bf16* d; long off;
  if (i4 < 32768) { s = tmw2; d = tmw2b; off = i4; }
  else if (i4 < 49152) { s = tdw2; d = tdw2b; off = i4 - 32768; }
  else if (i4 < 53248) { s = tkw2; d = tkw2b; off = i4 - 49152; }
  else if (i4 < 57344) { s = taw2; d = taw2b; off = i4 - 53248; }
  else if (i4 < 61440) { s = maw2; d = maw2b; off = i4 - 57344; }
  else { s = mkw2; d = mkw2b; off = i4 - 61440; }
  float4 v = *(const float4*)(s + off * 4);
  d[off * 4 + 0] = f2bf(v.x);
  d[off * 4 + 1] = f2bf(v.y);
  d[off * 4 + 2] = f2bf(v.z);
  d[off * 4 + 3] = f2bf(v.w);
}

// ---------------- K1: token shift (writes xx f32, xxx bf16) -----------------
__global__ __launch_bounds__(256) void shift_kernel(
    const float* __restrict__ x, const float* __restrict__ tmx,
    float* __restrict__ xx, bf16* __restrict__ xxxb) {
  long idx = (long)blockIdx.x * 256 + threadIdx.x;  // < B*T*C
  int c = (int)(idx & (C_ - 1));
  int t = (int)((idx >> 10) & (T_ - 1));
  float xv = x[idx];
  float xp = (t > 0) ? x[idx - C_] : 0.0f;
  float d = xp - xv;
  xx[idx] = d;
  xxxb[idx] = f2bf(xv + d * tmx[c]);
}

// ---------------- MFMA GEMM: C = A(bf16 MxK) * W^T (W bf16 NxK) -------------
__global__ __launch_bounds__(256) void gemm_mfma_kernel(
    const bf16* __restrict__ A, const bf16* __restrict__ W,
    float* __restrict__ Cf, bf16* __restrict__ Cb,
    int M, int N, int K, int actN) {
  __shared__ __align__(16) bf16 As[64][72];  // 144B row stride, 16B aligned
  __shared__ __align__(16) bf16 Ws[64][72];
  int tid = threadIdx.x;
  int m0 = blockIdx.y << 6, n0 = blockIdx.x << 6;
  int srow = tid >> 2, skg = (tid & 3) << 4;   // staging: row, 16 bf16 per thread
  int wv = tid >> 6, lane = tid & 63;
  int fr = lane & 15, fq = lane >> 4;
  f32x4 acc0 = {0.f, 0.f, 0.f, 0.f}, acc1 = acc0, acc2 = acc0, acc3 = acc0;
  bool wok = (n0 + srow) < N;
  const bf16* Ap = A + (long)(m0 + srow) * K + skg;
  const bf16* Wp = W + (long)(n0 + srow) * K + skg;
  short8 zz = {0, 0, 0, 0, 0, 0, 0, 0};
  for (int k0 = 0; k0 < K; k0 += 64) {
    *(short8*)&As[srow][skg] = *(const short8*)(Ap + k0);
    *(short8*)&As[srow][skg + 8] = *(const short8*)(Ap + k0 + 8);
    *(short8*)&Ws[srow][skg] = wok ? *(const short8*)(Wp + k0) : zz;
    *(short8*)&Ws[srow][skg + 8] = wok ? *(const short8*)(Wp + k0 + 8) : zz;
    __syncthreads();
#pragma unroll
    for (int kk = 0; kk < 2; kk++) {
      int ko = (fq << 3) + (kk << 5);
      short8 af = *(const short8*)&As[(wv << 4) + fr][ko];
      short8 b0 = *(const short8*)&Ws[fr][ko];
      short8 b1 = *(const short8*)&Ws[16 + fr][ko];
      short8 b2 = *(const short8*)&Ws[32 + fr][ko];
      short8 b3 = *(const short8*)&Ws[48 + fr][ko];
      acc0 = __builtin_amdgcn_mfma_f32_16x16x32_bf16(af, b0, acc0, 0, 0, 0);
      acc1 = __builtin_amdgcn_mfma_f32_16x16x32_bf16(af, b1, acc1, 0, 0, 0);
      acc2 = __builtin_amdgcn_mfma_f32_16x16x32_bf16(af, b2, acc2, 0, 0, 0);
      acc3 = __builtin_amdgcn_mfma_f32_16x16x32_bf16(af, b3, acc3, 0, 0, 0);
    }
    __syncthreads();
  }
  int orow = m0 + (wv << 4) + (fq << 2);
  int ocol = n0 + fr;
  f32x4 av[4] = {acc0, acc1, acc2, acc3};
#pragma unroll
  for (int nt = 0; nt < 4; nt++) {
    int col = ocol + (nt << 4);
    if (col < N) {
#pragma unroll
      for (int r = 0; r < 4; r++) {
        float vvv = av[nt][r];
        if (col < actN) vvv = tanhf(vvv);
        long oi = (long)(orow + r) * N + col;
        if (Cb) Cb[oi] = f2bf(vvv); else Cf[oi] = vvv;
      }
    }
  }
}

// ---------------- K3: deltas + build xrg/xwa/xk/xv (bf16 out) ---------------
__global__ __launch_bounds__(256) void mix4_kernel(
    const float* __restrict__ x, const float* __restrict__ xx,
    const float* __restrict__ mix, const float* __restrict__ tmaa,
    const bf16* __restrict__ w2b,
    bf16* __restrict__ xrg, bf16* __restrict__ xwa,
    bf16* __restrict__ xk, bf16* __restrict__ xv) {
  int m = blockIdx.x;
  int tid = threadIdx.x;
  __shared__ float mrow[128];
  if (tid < 128) mrow[tid] = mix[(long)m * 128 + tid];
  __syncthreads();
#pragma unroll
  for (int cc = 0; cc < 4; cc++) {
    int c = tid + (cc << 8);
    long off = (long)m * C_ + c;
    float xb = x[off];
    float xxv = xx[off];
    float res[4];
#pragma unroll
    for (int f = 0; f < 4; f++) {
      const short8* wp = (const short8*)(w2b + (((long)f * C_ + c) << 5));
      float dl = 0.f;
#pragma unroll
      for (int d8 = 0; d8 < 4; d8++) {
        short8 u = wp[d8];
        int db = (f << 5) + (d8 << 3);
#pragma unroll
        for (int e = 0; e < 8; e++) dl += mrow[db + e] * bs2f(u[e]);
      }
      res[f] = xb + xxv * (tmaa[f * C_ + c] + dl);
    }
    xrg[off] = f2bf(res[0]); xwa[off] = f2bf(res[1]);
    xk[off] = f2bf(res[2]); xv[off] = f2bf(res[3]);
  }
}

// ---------------- K5: stage-2 small GEMMs + gates + per-head kk norm --------
__global__ __launch_bounds__(256) void fuse2_kernel(
    const float* __restrict__ kraw, const float* __restrict__ out1,
    const float* __restrict__ out2,
    const bf16* __restrict__ dw2, const bf16* __restrict__ kkw2,
    const bf16* __restrict__ aw2, const bf16* __restrict__ maw2,
    const bf16* __restrict__ mkw2,
    const float* __restrict__ tdec, const float* __restrict__ taa,
    const float* __restrict__ tma, const float* __restrict__ tmk,
    float* __restrict__ ew, float* __restrict__ kfin,
    float* __restrict__ kkn, float* __restrict__ bbo) {
  int m = blockIdx.x, tid = threadIdx.x;
  __shared__ float w1r[64], kk1r[16], a1r[16], ma1r[16], mk1r[16];
  if (tid < 64) w1r[tid] = out2[(long)m * 96 + tid];
  else if (tid < 80) kk1r[tid - 64] = out1[(long)m * 32 + (tid - 64)];
  else if (tid < 96) a1r[tid - 80] = out2[(long)m * 96 + 64 + (tid - 80)];
  else if (tid < 112) ma1r[tid - 96] = out2[(long)m * 96 + 80 + (tid - 96)];
  else if (tid < 128) mk1r[tid - 112] = out1[(long)m * 32 + 16 + (tid - 112)];
  __syncthreads();
  float kkp[4], av[4], wv[4], kr[4], mkv[4];
  float sumsq = 0.f;
#pragma unroll
  for (int j = 0; j < 4; j++) {
    int c = (tid << 2) + j;
    long off = (long)m * C_ + c;
    float wd = 0.f;
    const short8* dp = (const short8*)(dw2 + ((long)c << 6));
#pragma unroll
    for (int d8 = 0; d8 < 8; d8++) {
      short8 u = dp[d8];
      int db = d8 << 3;
#pragma unroll
      for (int e = 0; e < 8; e++) wd += w1r[db + e] * bs2f(u[e]);
    }
    float w = -softplusf_(-(tdec[c] + wd)) - 0.5f;
    wv[j] = w;
    float kd = 0.f, ad = 0.f, mad = 0.f, mkd = 0.f;
    const short8* kp = (const short8*)(kkw2 + ((long)c << 4));
    const short8* ap = (const short8*)(aw2 + ((long)c << 4));
    const short8* mp = (const short8*)(maw2 + ((long)c << 4));
    const short8* qp = (const short8*)(mkw2 + ((long)c << 4));
#pragma unroll
    for (int d8 = 0; d8 < 2; d8++) {
      short8 u1 = kp[d8], u2 = ap[d8], u3 = mp[d8], u4 = qp[d8];
      int db = d8 << 3;
#pragma unroll
      for (int e = 0; e < 8; e++) {
        kd += kk1r[db + e] * bs2f(u1[e]);
        ad += a1r[db + e] * bs2f(u2[e]);
        mad += ma1r[db + e] * bs2f(u3[e]);
        mkd += mk1r[db + e] * bs2f(u4[e]);
      }
    }
    float krw = kraw[off];
    float kkpre = krw + kd;
    kkp[j] = kkpre;
    sumsq += kkpre * kkpre;
    float a = sigmoidf_(taa[c] + ad);
    av[j] = a;
    float ma = sigmoidf_(tma[c] + mad);
    float mk = sigmoidf_(tmk[c] + mkd);
    mkv[j] = mk;
    kr[j] = krw * (ma + a * (1.f - ma));
  }
  sumsq += __shfl_xor(sumsq, 1);
  sumsq += __shfl_xor(sumsq, 2);
  sumsq += __shfl_xor(sumsq, 4);
  sumsq += __shfl_xor(sumsq, 8);
  float rn = 1.0f / fmaxf(sqrtf(sumsq), 1e-12f);
#pragma unroll
  for (int j = 0; j < 4; j++) {
    int c = (tid << 2) + j;
    long off = (long)m * C_ + c;
    float kknv = kkp[j] * rn;
    kkn[off] = kknv;
    bbo[off] = -kknv * av[j];
    ew[off] = expf(wv[j]);
    kfin[off] = kr[j] * expf(wv[j] * mkv[j]);
  }
}

// ---------------- K6: RWKV-7 scan, 128 blocks x 256 threads -----------------
// block = (b,h,rowgroup of 16 rows). Lane = g*16+q: row = rg*16 + wave*4 + g,
// keys 4q..4q+3 -> S[4]/lane. Reductions over 16 q-lanes via qsum16 (DPP).
// Round 14: LDS staging removed entirely. The stream data per (b,h) is 1.5MB
// and read at full-wave granularity (4 g-lanes share each float4; coalescer +
// L1 absorb the duplication), so global->LDS->reg was pure overhead AND the
// compiler refused to keep a 2-deep LDS-read pipeline live (VGPR stayed 48).
// Now: each lane loads its own 5 float4 slices + v directly from global with
// an explicit 4-deep rotating pipeline (4 NAMED buffer sets, manual unroll x4,
// static register indexing per rule #20). Load->use distance ~4 tokens covers
// L1/L2 latency. No barriers, no LDS. launch_bounds(256,1) keeps the register
// file open (~21 VGPR/token-set x 4 sets + state).
__global__ __launch_bounds__(256, 1) void scan_kernel(
    const float* __restrict__ rB, const float* __restrict__ ewB,
    const float* __restrict__ kB, const float* __restrict__ vB,
    const float* __restrict__ kkB, const float* __restrict__ bbB,
    float* __restrict__ yB) {
  int bid = blockIdx.x;          // 0..127
  int bh = bid >> 2, rg = bid & 3;
  int b = bh >> 4, h = bh & 15;
  int tid = threadIdx.x;
  int wave = tid >> 6, lane = tid & 63;
  int g = lane >> 4, q = lane & 15;
  int row = (rg << 4) + (wave << 2) + g;   // this lane's single row
  int kq = q << 2;                         // 4 keys: kq..kq+3
  const long base = ((long)b * T_) * C_ + (h << 6);
  const float* p0 = kkB + base + kq;
  const float* p1 = ewB + base + kq;
  const float* p2 = kB + base + kq;
  const float* p3 = bbB + base + kq;
  const float* p4 = rB + base + kq;
  const float* p5 = vB + base + row;
  float S0v = 0.f, S1v = 0.f, S2v = 0.f, S3v = 0.f;
  float4 A_kk, A_ew, A_k, A_bb, A_r; float A_v;
  float4 B_kk, B_ew, B_k, B_bb, B_r; float B_v;
  float4 C_kk, C_ew, C_k, C_bb, C_r; float C_v;
  float4 D_kk, D_ew, D_k, D_bb, D_r; float D_v;

#define LOADS(S, tok) { \
    long _o = (long)(tok) * C_; \
    S##_kk = *(const float4*)(p0 + _o); \
    S##_ew = *(const float4*)(p1 + _o); \
    S##_k  = *(const float4*)(p2 + _o); \
    S##_bb = *(const float4*)(p3 + _o); \
    S##_r  = *(const float4*)(p4 + _o); \
    S##_v  = *(p5 + _o); }

#define STEP(S, tok) { \
    float p_ = fmaf(S1v, S##_kk.y, S0v * S##_kk.x) + \
               fmaf(S3v, S##_kk.w, S2v * S##_kk.z); \
    float sab = qsum16(p_); \
    float n0 = fmaf(S0v, S##_ew.x, S##_v * S##_k.x); \
    float n1 = fmaf(S1v, S##_ew.y, S##_v * S##_k.y); \
    float n2 = fmaf(S2v, S##_ew.z, S##_v * S##_k.z); \
    float n3 = fmaf(S3v, S##_ew.w, S##_v * S##_k.w); \
    S0v = fmaf(sab, S##_bb.x, n0); \
    S1v = fmaf(sab, S##_bb.y, n1); \
    S2v = fmaf(sab, S##_bb.z, n2); \
    S3v = fmaf(sab, S##_bb.w, n3); \
    float yp_ = fmaf(S1v, S##_r.y, S0v * S##_r.x) + \
                fmaf(S3v, S##_r.w, S2v * S##_r.z); \
    float yv_ = qsum16(yp_); \
    if (q == 0) yB[base + (long)(tok) * C_ + row] = yv_; }

  LOADS(A, 0); LOADS(B, 1); LOADS(C, 2); LOADS(D, 3);
  int t = 0;
  for (; t < T_ - 4; t += 4) {
    STEP(A, t);     LOADS(A, t + 4);
    STEP(B, t + 1); LOADS(B, t + 5);
    STEP(C, t + 2); LOADS(C, t + 6);
    STEP(D, t + 3); LOADS(D, t + 7);
  }
  STEP(A, t); STEP(B, t + 1); STEP(C, t + 2); STEP(D, t + 3);
#undef LOADS
#undef STEP
}

// ---------------- K7: GroupNorm + bonus + gate (bf16 out) -------------------
__global__ __launch_bounds__(256) void gnout_kernel(
    const float* __restrict__ y, const float* __restrict__ r,
    const float* __restrict__ kf, const float* __restrict__ v,
    const float* __restrict__ g,
    const float* __restrict__ lnw, const float* __restrict__ lnb,
    const float* __restrict__ fa, bf16* __restrict__ z) {
  int tid = threadIdx.x;
  int w = tid >> 6, lane = tid & 63;
  int gi = (blockIdx.x << 2) + w;  // (b*T+t)*H + h
  int h = gi & 15, mt = gi >> 4;
  long off = (long)mt * C_ + (h << 6) + lane;
  float yv = y[off];
  float s = yv;
  s += __shfl_xor(s, 1); s += __shfl_xor(s, 2); s += __shfl_xor(s, 4);
  s += __shfl_xor(s, 8); s += __shfl_xor(s, 16); s += __shfl_xor(s, 32);
  float mu = s * (1.0f / 64.0f);
  float d = yv - mu;
  float s2 = d * d;
  s2 += __shfl_xor(s2, 1); s2 += __shfl_xor(s2, 2); s2 += __shfl_xor(s2, 4);
  s2 += __shfl_xor(s2, 8); s2 += __shfl_xor(s2, 16); s2 += __shfl_xor(s2, 32);
  float var = s2 * (1.0f / 64.0f);
  int hc = (h << 6) + lane;
  float dot = r[off] * kf[off] * fa[hc];
  dot += __shfl_xor(dot, 1); dot += __shfl_xor(dot, 2); dot += __shfl_xor(dot, 4);
  dot += __shfl_xor(dot, 8); dot += __shfl_xor(dot, 16); dot += __shfl_xor(dot, 32);
  float yn = d * rsqrtf(var + 0.00064f) * lnw[hc] + lnb[hc];
  z[off] = f2bf((yn + dot * v[off]) * g[off]);
}

extern "C" void kernel_launch(void* const* d_in, const int* in_sizes, int n_in,
                              void* d_out, int out_size, void* d_ws, size_t ws_size,
                              hipStream_t stream) {
  const float* x = (const float*)d_in[0];
  const float* tmx = (const float*)d_in[1];
  const float* tmaa = (const float*)d_in[2];
  const float* tmw1 = (const float*)d_in[3];
  const float* tmw2 = (const float*)d_in[4];
  const float* tdec = (const float*)d_in[5];
  const float* tdw1 = (const float*)d_in[6];
  const float* tdw2 = (const float*)d_in[7];
  const float* taa5 = (const float*)d_in[8];
  const float* taw1 = (const float*)d_in[9];
  const float* taw2 = (const float*)d_in[10];
  const float* tkw1 = (const float*)d_in[11];
  const float* tkw2 = (const float*)d_in[12];
  const float* gw1 = (const float*)d_in[13];
  const float* gw2 = (const float*)d_in[14];
  const float* tmia = (const float*)d_in[15];
  const float* maw1 = (const float*)d_in[16];
  const float* maw2 = (const float*)d_in[17];
  const float* tmik = (const float*)d_in[18];
  const float* mkw1 = (const float*)d_in[19];
  const float* mkw2 = (const float*)d_in[20];
  const float* wrec = (const float*)d_in[21];
  const float* wkey = (const float*)d_in[22];
  const float* wval = (const float*)d_in[23];
  const float* wout = (const float*)d_in[24];
  const float* lnw = (const float*)d_in[25];
  const float* lnb = (const float*)d_in[26];
  const float* faaa = (const float*)d_in[27];

  const long MT = 2048, CC = 1024;
  char* base = (char*)d_ws;
  float* xx = (float*)base;    base += MT * CC * 4;   // also y
  bf16* xxxb = (bf16*)base;    base += MT * CC * 2;
  bf16* xrgb = (bf16*)base;    base += MT * CC * 2;   // ┐ kfin overlays (8MB)
  bf16* xwab = (bf16*)base;    base += MT * CC * 2;   // ┘
  bf16* xkb = (bf16*)base;     base += MT * CC * 2;   // ┐ kkn overlays (8MB)
  bf16* xvb = (bf16*)base;     base += MT * CC * 2;   // ┘
  float* rr = (float*)base;    base += MT * CC * 4;
  float* kraw = (float*)base;  base += MT * CC * 4;   // also ew
  float* vv = (float*)base;    base += MT * CC * 4;
  float* gg = (float*)base;    base += MT * CC * 4;
  float* bbo = (float*)base;   base += MT * CC * 4;
  float* mix = (float*)base;   base += MT * 128 * 4;
  bf16* g1b = (bf16*)base;     base += MT * 128 * 2;
  float* out1 = (float*)base;  base += MT * 32 * 4;   // [kk1|mk1]
  float* out2 = (float*)base;  base += MT * 96 * 4;   // [w1|a1|ma1]
  bf16* zb = (bf16*)base;      base += MT * CC * 2;
  bf16* tmw1b = (bf16*)base;   base += 128 * CC * 2;
  bf16* wrecb = (bf16*)base;   base += CC * CC * 2;
  bf16* gw1b = (bf16*)base;    base += 128 * CC * 2;
  bf16* gw2b = (bf16*)base;    base += CC * 128 * 2;
  bf16* wkeyb = (bf16*)base;   base += CC * CC * 2;
  bf16* wvalb = (bf16*)base;   base += CC * CC * 2;
  bf16* woutb = (bf16*)base;   base += CC * CC * 2;
  bf16* wskb = (bf16*)base;    base += 32 * CC * 2;
  bf16* wswab = (bf16*)base;   base += 96 * CC * 2;
  bf16* tmw2b = (bf16*)base;   base += 4 * CC * 32 * 2;
  bf16* tdw2b = (bf16*)base;   base += CC * 64 * 2;
  bf16* tkw2b = (bf16*)base;   base += CC * 16 * 2;
  bf16* taw2b = (bf16*)base;   base += CC * 16 * 2;
  bf16* maw2b = (bf16*)base;   base += CC * 16 * 2;
  bf16* mkw2b = (bf16*)base;   base += CC * 16 * 2;
  // aliases (dead-buffer reuse, verified non-overlapping in time):
  float* ew = kraw;            // fuse2 reads kraw then writes ew at same offs
  float* kfin = (float*)xrgb;  // xrg/xwa bf16 dead before fuse2
  float* kkn = (float*)xkb;    // xk/xv bf16 dead before fuse2
  float* y = xx;               // xx dead after mix4

  auto gemm_m = [&](const bf16* A, const bf16* W, float* Cf, bf16* Cb,
                    int M, int N, int K, int actN) {
    dim3 grid((N + 63) / 64, M / 64);
    gemm_mfma_kernel<<<grid, 256, 0, stream>>>(A, W, Cf, Cb, M, N, K, actN);
  };

  cvt_weights_kernel<<<4480, 256, 0, stream>>>(
      tmw1, wrec, gw1, gw2, wkey, wval, wout,
      tmw1b, wrecb, gw1b, gw2b, wkeyb, wvalb, woutb);
  cvt_small_kernel<<<128, 256, 0, stream>>>(tkw1, mkw1, tdw1, taw1, maw1,
                                            wskb, wswab);
  cvt_small2_kernel<<<256, 256, 0, stream>>>(tmw2, tdw2, tkw2, taw2, maw2, mkw2,
                                             tmw2b, tdw2b, tkw2b, taw2b,
                                             maw2b, mkw2b);
  shift_kernel<<<8192, 256, 0, stream>>>(x, tmx, xx, xxxb);
  gemm_m(xxxb, tmw1b, mix, nullptr, 2048, 128, 1024, 128);   // tanh all
  mix4_kernel<<<2048, 256, 0, stream>>>(x, xx, mix, tmaa, tmw2b,
                                        xrgb, xwab, xkb, xvb);
  gemm_m(xrgb, wrecb, rr, nullptr, 2048, 1024, 1024, 0);
  gemm_m(xrgb, gw1b, nullptr, g1b, 2048, 128, 1024, 128);    // tanh all
  gemm_m(g1b, gw2b, gg, nullptr, 2048, 1024, 128, 0);
  gemm_m(xkb, wkeyb, kraw, nullptr, 2048, 1024, 1024, 0);
  gemm_m(xkb, wskb, out1, nullptr, 2048, 32, 1024, 16);      // tanh cols<16
  gemm_m(xvb, wvalb, vv, nullptr, 2048, 1024, 1024, 0);
  gemm_m(xwab, wswab, out2, nullptr, 2048, 96, 1024, 64);    // tanh cols<64
  fuse2_kernel<<<2048, 256, 0, stream>>>(kraw, out1, out2,
                                         tdw2b, tkw2b, taw2b, maw2b, mkw2b,
                                         tdec, taa5, tmia, tmik,
                                         ew, kfin, kkn, bbo);
  scan_kernel<<<128, 256, 0, stream>>>(rr, ew, kfin, vv, kkn, bbo, y);
  gnout_kernel<<<8192, 256, 0, stream>>>(y, rr, kfin, vv, gg, lnw, lnb, faaa, zb);
  gemm_m(zb, woutb, (float*)d_out, nullptr, 2048, 1024, 1024, 0);
}

// Round 3
// 644.608 us; speedup vs baseline: 1.2688x; 1.2688x over previous
//
#include <hip/hip_runtime.h>
#include <hip/hip_bf16.h>

typedef __hip_bfloat16 bf16;

#define B_ 2
#define T_ 1024
#define C_ 1024
#define H_ 16
#define N_ 64

using short8 = __attribute__((ext_vector_type(8))) short;
using f32x4 = __attribute__((ext_vector_type(4))) float;

__device__ __forceinline__ float us2f(unsigned short u) {
  return __uint_as_float(((unsigned int)u) << 16);
}
__device__ __forceinline__ float bs2f(short s) {
  return __uint_as_float(((unsigned int)(unsigned short)s) << 16);
}
__device__ __forceinline__ bf16 f2bf(float f) { return __float2bfloat16(f); }
__device__ __forceinline__ float sigmoidf_(float x) { return 1.0f / (1.0f + expf(-x)); }
__device__ __forceinline__ float softplusf_(float x) {
  return fmaxf(x, 0.0f) + log1pf(expf(-fabsf(x)));
}
// Full 16-lane-row sum, all lanes receive the result. Pure-VALU DPP:
// quad_perm xor1, xor2 give quad sums; row_ror:4 + row_ror:8 complete it.
__device__ __forceinline__ float qsum16(float x) {
  int a = __builtin_amdgcn_update_dpp(0, __float_as_int(x), 0xB1, 0xF, 0xF, true);
  x += __int_as_float(a);                       // quad_perm [1,0,3,2] (xor 1)
  int b = __builtin_amdgcn_update_dpp(0, __float_as_int(x), 0x4E, 0xF, 0xF, true);
  x += __int_as_float(b);                       // quad_perm [2,3,0,1] (xor 2)
  int c = __builtin_amdgcn_update_dpp(0, __float_as_int(x), 0x124, 0xF, 0xF, true);
  x += __int_as_float(c);                       // row_ror:4
  int d = __builtin_amdgcn_update_dpp(0, __float_as_int(x), 0x128, 0xF, 0xF, true);
  x += __int_as_float(d);                       // row_ror:8
  return x;
}

// ---------------- K0: fused weight fp32->bf16 conversion (big weights) ------
__global__ __launch_bounds__(256) void cvt_weights_kernel(
    const float* __restrict__ s0, const float* __restrict__ s1,
    const float* __restrict__ s2, const float* __restrict__ s3,
    const float* __restrict__ s4, const float* __restrict__ s5,
    const float* __restrict__ s6,
    bf16* __restrict__ d0, bf16* __restrict__ d1, bf16* __restrict__ d2,
    bf16* __restrict__ d3, bf16* __restrict__ d4, bf16* __restrict__ d5,
    bf16* __restrict__ d6) {
  long i4 = (long)blockIdx.x * 256 + threadIdx.x;
  const float* s; bf16* d; long off;
  if (i4 < 32768) { s = s0; d = d0; off = i4; }
  else if (i4 < 294912) { s = s1; d = d1; off = i4 - 32768; }
  else if (i4 < 327680) { s = s2; d = d2; off = i4 - 294912; }
  else if (i4 < 360448) { s = s3; d = d3; off = i4 - 327680; }
  else if (i4 < 622592) { s = s4; d = d4; off = i4 - 360448; }
  else if (i4 < 884736) { s = s5; d = d5; off = i4 - 622592; }
  else { s = s6; d = d6; off = i4 - 884736; }
  float4 v = *(const float4*)(s + off * 4);
  d[off * 4 + 0] = f2bf(v.x);
  d[off * 4 + 1] = f2bf(v.y);
  d[off * 4 + 2] = f2bf(v.z);
  d[off * 4 + 3] = f2bf(v.w);
}

// ---------------- K0b: pack small LoRA-1 weights to bf16 --------------------
__global__ __launch_bounds__(256) void cvt_small_kernel(
    const float* __restrict__ tkw1, const float* __restrict__ mkw1,
    const float* __restrict__ tdw1, const float* __restrict__ taw1,
    const float* __restrict__ maw1,
    bf16* __restrict__ wsk, bf16* __restrict__ wswa) {
  long i4 = (long)blockIdx.x * 256 + threadIdx.x;  // < 32768
  const float* s; bf16* d; long so, dof;
  if (i4 < 4096) { s = tkw1; so = i4; d = wsk; dof = i4; }
  else if (i4 < 8192) { s = mkw1; so = i4 - 4096; d = wsk; dof = i4; }
  else if (i4 < 24576) { s = tdw1; so = i4 - 8192; d = wswa; dof = i4 - 8192; }
  else if (i4 < 28672) { s = taw1; so = i4 - 24576; d = wswa; dof = i4 - 8192; }
  else { s = maw1; so = i4 - 28672; d = wswa; dof = i4 - 8192; }
  float4 v = *(const float4*)(s + so * 4);
  d[dof * 4 + 0] = f2bf(v.x);
  d[dof * 4 + 1] = f2bf(v.y);
  d[dof * 4 + 2] = f2bf(v.z);
  d[dof * 4 + 3] = f2bf(v.w);
}

// ---------------- K0c: LoRA-2 weights to bf16 -------------------------------
__global__ __launch_bounds__(256) void cvt_small2_kernel(
    const float* __restrict__ tmw2, const float* __restrict__ tdw2,
    const float* __restrict__ tkw2, const float* __restrict__ taw2,
    const float* __restrict__ maw2, const float* __restrict__ mkw2,
    bf16* __restrict__ tmw2b, bf16* __restrict__ tdw2b,
    bf16* __restrict__ tkw2b, bf16* __restrict__ taw2b,
    bf16* __restrict__ maw2b, bf16* __restrict__ mkw2b) {
  long i4 = (long)blockIdx.x * 256 + threadIdx.x;  // < 65536
  const float* s; bf16* d; long off;
  if (i4 < 32768) { s = tmw2; d = tmw2b; off = i4; }
  else if (i4 < 49152) { s = tdw2; d = tdw2b; off = i4 - 32768; }
  else if (i4 < 53248) { s = tkw2; d = tkw2b; off = i4 - 49152; }
  else if (i4 < 57344) { s = taw2; d = taw2b; off = i4 - 53248; }
  else if (i4 < 61440) { s = maw2; d = maw2b; off = i4 - 57344; }
  else { s = mkw2; d = mkw2b; off = i4 - 61440; }
  float4 v = *(const float4*)(s + off * 4);
  d[off * 4 + 0] = f2bf(v.x);
  d[off * 4 + 1] = f2bf(v.y);
  d[off * 4 + 2] = f2bf(v.z);
  d[off * 4 + 3] = f2bf(v.w);
}

// ---------------- K1: token shift (writes xx f32, xxx bf16) -----------------
__global__ __launch_bounds__(256) void shift_kernel(
    const float* __restrict__ x, const float* __restrict__ tmx,
    float* __restrict__ xx, bf16* __restrict__ xxxb) {
  long idx = (long)blockIdx.x * 256 + threadIdx.x;  // < B*T*C
  int c = (int)(idx & (C_ - 1));
  int t = (int)((idx >> 10) & (T_ - 1));
  float xv = x[idx];
  float xp = (t > 0) ? x[idx - C_] : 0.0f;
  float d = xp - xv;
  xx[idx] = d;
  xxxb[idx] = f2bf(xv + d * tmx[c]);
}

// ---------------- MFMA GEMM: C = A(bf16 MxK) * W^T (W bf16 NxK) -------------
__global__ __launch_bounds__(256) void gemm_mfma_kernel(
    const bf16* __restrict__ A, const bf16* __restrict__ W,
    float* __restrict__ Cf, bf16* __restrict__ Cb,
    int M, int N, int K, int actN) {
  __shared__ __align__(16) bf16 As[64][72];  // 144B row stride, 16B aligned
  __shared__ __align__(16) bf16 Ws[64][72];
  int tid = threadIdx.x;
  int m0 = blockIdx.y << 6, n0 = blockIdx.x << 6;
  int srow = tid >> 2, skg = (tid & 3) << 4;   // staging: row, 16 bf16 per thread
  int wv = tid >> 6, lane = tid & 63;
  int fr = lane & 15, fq = lane >> 4;
  f32x4 acc0 = {0.f, 0.f, 0.f, 0.f}, acc1 = acc0, acc2 = acc0, acc3 = acc0;
  bool wok = (n0 + srow) < N;
  const bf16* Ap = A + (long)(m0 + srow) * K + skg;
  const bf16* Wp = W + (long)(n0 + srow) * K + skg;
  short8 zz = {0, 0, 0, 0, 0, 0, 0, 0};
  for (int k0 = 0; k0 < K; k0 += 64) {
    *(short8*)&As[srow][skg] = *(const short8*)(Ap + k0);
    *(short8*)&As[srow][skg + 8] = *(const short8*)(Ap + k0 + 8);
    *(short8*)&Ws[srow][skg] = wok ? *(const short8*)(Wp + k0) : zz;
    *(short8*)&Ws[srow][skg + 8] = wok ? *(const short8*)(Wp + k0 + 8) : zz;
    __syncthreads();
#pragma unroll
    for (int kk = 0; kk < 2; kk++) {
      int ko = (fq << 3) + (kk << 5);
      short8 af = *(const short8*)&As[(wv << 4) + fr][ko];
      short8 b0 = *(const short8*)&Ws[fr][ko];
      short8 b1 = *(const short8*)&Ws[16 + fr][ko];
      short8 b2 = *(const short8*)&Ws[32 + fr][ko];
      short8 b3 = *(const short8*)&Ws[48 + fr][ko];
      acc0 = __builtin_amdgcn_mfma_f32_16x16x32_bf16(af, b0, acc0, 0, 0, 0);
      acc1 = __builtin_amdgcn_mfma_f32_16x16x32_bf16(af, b1, acc1, 0, 0, 0);
      acc2 = __builtin_amdgcn_mfma_f32_16x16x32_bf16(af, b2, acc2, 0, 0, 0);
      acc3 = __builtin_amdgcn_mfma_f32_16x16x32_bf16(af, b3, acc3, 0, 0, 0);
    }
    __syncthreads();
  }
  int orow = m0 + (wv << 4) + (fq << 2);
  int ocol = n0 + fr;
  f32x4 av[4] = {acc0, acc1, acc2, acc3};
#pragma unroll
  for (int nt = 0; nt < 4; nt++) {
    int col = ocol + (nt << 4);
    if (col < N) {
#pragma unroll
      for (int r = 0; r < 4; r++) {
        float vvv = av[nt][r];
        if (col < actN) vvv = tanhf(vvv);
        long oi = (long)(orow + r) * N + col;
        if (Cb) Cb[oi] = f2bf(vvv); else Cf[oi] = vvv;
      }
    }
  }
}

// ---------------- K3: deltas + build xrg/xwa/xk/xv (bf16 out) ---------------
__global__ __launch_bounds__(256) void mix4_kernel(
    const float* __restrict__ x, const float* __restrict__ xx,
    const float* __restrict__ mix, const float* __restrict__ tmaa,
    const bf16* __restrict__ w2b,
    bf16* __restrict__ xrg, bf16* __restrict__ xwa,
    bf16* __restrict__ xk, bf16* __restrict__ xv) {
  int m = blockIdx.x;
  int tid = threadIdx.x;
  __shared__ float mrow[128];
  if (tid < 128) mrow[tid] = mix[(long)m * 128 + tid];
  __syncthreads();
#pragma unroll
  for (int cc = 0; cc < 4; cc++) {
    int c = tid + (cc << 8);
    long off = (long)m * C_ + c;
    float xb = x[off];
    float xxv = xx[off];
    float res[4];
#pragma unroll
    for (int f = 0; f < 4; f++) {
      const short8* wp = (const short8*)(w2b + (((long)f * C_ + c) << 5));
      float dl = 0.f;
#pragma unroll
      for (int d8 = 0; d8 < 4; d8++) {
        short8 u = wp[d8];
        int db = (f << 5) + (d8 << 3);
#pragma unroll
        for (int e = 0; e < 8; e++) dl += mrow[db + e] * bs2f(u[e]);
      }
      res[f] = xb + xxv * (tmaa[f * C_ + c] + dl);
    }
    xrg[off] = f2bf(res[0]); xwa[off] = f2bf(res[1]);
    xk[off] = f2bf(res[2]); xv[off] = f2bf(res[3]);
  }
}

// ---------------- K5: stage-2 small GEMMs + gates + per-head kk norm --------
__global__ __launch_bounds__(256) void fuse2_kernel(
    const float* __restrict__ kraw, const float* __restrict__ out1,
    const float* __restrict__ out2,
    const bf16* __restrict__ dw2, const bf16* __restrict__ kkw2,
    const bf16* __restrict__ aw2, const bf16* __restrict__ maw2,
    const bf16* __restrict__ mkw2,
    const float* __restrict__ tdec, const float* __restrict__ taa,
    const float* __restrict__ tma, const float* __restrict__ tmk,
    float* __restrict__ ew, float* __restrict__ kfin,
    float* __restrict__ kkn, float* __restrict__ bbo) {
  int m = blockIdx.x, tid = threadIdx.x;
  __shared__ float w1r[64], kk1r[16], a1r[16], ma1r[16], mk1r[16];
  if (tid < 64) w1r[tid] = out2[(long)m * 96 + tid];
  else if (tid < 80) kk1r[tid - 64] = out1[(long)m * 32 + (tid - 64)];
  else if (tid < 96) a1r[tid - 80] = out2[(long)m * 96 + 64 + (tid - 80)];
  else if (tid < 112) ma1r[tid - 96] = out2[(long)m * 96 + 80 + (tid - 96)];
  else if (tid < 128) mk1r[tid - 112] = out1[(long)m * 32 + 16 + (tid - 112)];
  __syncthreads();
  float kkp[4], av[4], wv[4], kr[4], mkv[4];
  float sumsq = 0.f;
#pragma unroll
  for (int j = 0; j < 4; j++) {
    int c = (tid << 2) + j;
    long off = (long)m * C_ + c;
    float wd = 0.f;
    const short8* dp = (const short8*)(dw2 + ((long)c << 6));
#pragma unroll
    for (int d8 = 0; d8 < 8; d8++) {
      short8 u = dp[d8];
      int db = d8 << 3;
#pragma unroll
      for (int e = 0; e < 8; e++) wd += w1r[db + e] * bs2f(u[e]);
    }
    float w = -softplusf_(-(tdec[c] + wd)) - 0.5f;
    wv[j] = w;
    float kd = 0.f, ad = 0.f, mad = 0.f, mkd = 0.f;
    const short8* kp = (const short8*)(kkw2 + ((long)c << 4));
    const short8* ap = (const short8*)(aw2 + ((long)c << 4));
    const short8* mp = (const short8*)(maw2 + ((long)c << 4));
    const short8* qp = (const short8*)(mkw2 + ((long)c << 4));
#pragma unroll
    for (int d8 = 0; d8 < 2; d8++) {
      short8 u1 = kp[d8], u2 = ap[d8], u3 = mp[d8], u4 = qp[d8];
      int db = d8 << 3;
#pragma unroll
      for (int e = 0; e < 8; e++) {
        kd += kk1r[db + e] * bs2f(u1[e]);
        ad += a1r[db + e] * bs2f(u2[e]);
        mad += ma1r[db + e] * bs2f(u3[e]);
        mkd += mk1r[db + e] * bs2f(u4[e]);
      }
    }
    float krw = kraw[off];
    float kkpre = krw + kd;
    kkp[j] = kkpre;
    sumsq += kkpre * kkpre;
    float a = sigmoidf_(taa[c] + ad);
    av[j] = a;
    float ma = sigmoidf_(tma[c] + mad);
    float mk = sigmoidf_(tmk[c] + mkd);
    mkv[j] = mk;
    kr[j] = krw * (ma + a * (1.f - ma));
  }
  sumsq += __shfl_xor(sumsq, 1);
  sumsq += __shfl_xor(sumsq, 2);
  sumsq += __shfl_xor(sumsq, 4);
  sumsq += __shfl_xor(sumsq, 8);
  float rn = 1.0f / fmaxf(sqrtf(sumsq), 1e-12f);
#pragma unroll
  for (int j = 0; j < 4; j++) {
    int c = (tid << 2) + j;
    long off = (long)m * C_ + c;
    float kknv = kkp[j] * rn;
    kkn[off] = kknv;
    bbo[off] = -kknv * av[j];
    ew[off] = expf(wv[j]);
    kfin[off] = kr[j] * expf(wv[j] * mkv[j]);
  }
}

// ---------------- K6: RWKV-7 scan, 128 blocks x 256 threads -----------------
// block = (b,h,rowgroup of 16 rows). Lane = g*16+q: row = rg*16 + wave*4 + g,
// keys 4q..4q+3 -> S[4]/lane. Reductions over 16 q-lanes via qsum16 (DPP).
// Round 15: back to LDS chunking (R2's direct-global variant lost the 16-token
// prefetch distance and went latency-bound at L3 latency; 135 -> 308 us).
// This version keeps the verified R1 chunk structure and adds:
//  (a) double-buffered LDS (one barrier per 16-token chunk, staging of chunk
//      c+1 overlaps compute of chunk c; global loads for c+2 issued at top),
//  (b) an explicit 3-set rotating register pipeline reading LDS 2 tokens
//      ahead (static names only, no runtime-indexed arrays),
//  (c) sched_barrier(0x7) after each prefetch block: VALU/SALU may cross
//      (keeps cross-token ILP) but DS ops may not -- prevents the scheduler
//      from collapsing the pipeline (R1 collapsed to VGPR=48, waiting ~120cy
//      of ds_read latency every token).
// Expected floor: LDS pipe ~170 cyc/token (4 waves x ~5.3KB/token, 128B/clk).
#define SCHUNK 16
#define NCHUNK (T_ / SCHUNK)
__global__ __launch_bounds__(256, 1) void scan_kernel(
    const float* __restrict__ rB, const float* __restrict__ ewB,
    const float* __restrict__ kB, const float* __restrict__ vB,
    const float* __restrict__ kkB, const float* __restrict__ bbB,
    float* __restrict__ yB) {
  __shared__ __align__(16) float lds[2][6][SCHUNK * 64];
  int bid = blockIdx.x;          // 0..127
  int bh = bid >> 2, rg = bid & 3;
  int b = bh >> 4, h = bh & 15;
  int tid = threadIdx.x;
  int wave = tid >> 6, lane = tid & 63;
  int g = lane >> 4, q = lane & 15;
  int row = (rg << 4) + (wave << 2) + g;   // this lane's single row
  int kq = q << 2;                         // 4 keys: kq..kq+3
  const long base = ((long)b * T_) * C_ + (h << 6);
  const float* s0 = kkB + base;
  const float* s1 = ewB + base;
  const float* s2 = kB + base;
  const float* s3 = bbB + base;
  const float* s4 = rB + base;
  const float* s5 = vB + base;
  int stok = tid >> 4;           // staging token within chunk (0..15)
  int spc = (tid & 15) << 2;     // float offset within token row
  int lo = (stok << 6) + spc;    // LDS float offset
  float4 rb0, rb1, rb2, rb3, rb4, rb5;
  auto loadc = [&](int c) {
    long go = (long)((c << 4) + stok) * C_ + spc;
    rb0 = *(const float4*)(s0 + go);
    rb1 = *(const float4*)(s1 + go);
    rb2 = *(const float4*)(s2 + go);
    rb3 = *(const float4*)(s3 + go);
    rb4 = *(const float4*)(s4 + go);
    rb5 = *(const float4*)(s5 + go);
  };
  auto stage = [&](int buf) {
    *(float4*)&lds[buf][0][lo] = rb0;
    *(float4*)&lds[buf][1][lo] = rb1;
    *(float4*)&lds[buf][2][lo] = rb2;
    *(float4*)&lds[buf][3][lo] = rb3;
    *(float4*)&lds[buf][4][lo] = rb4;
    *(float4*)&lds[buf][5][lo] = rb5;
  };
  float S0 = 0.f, S1 = 0.f, S2 = 0.f, S3 = 0.f;
  // 3 rotating prefetch sets (static names; token tt uses set tt%3)
  float4 Q0kk, Q0ew, Q0k, Q0bb, Q0r; float Q0v;
  float4 Q1kk, Q1ew, Q1k, Q1bb, Q1r; float Q1v;
  float4 Q2kk, Q2ew, Q2k, Q2bb, Q2r; float Q2v;

#define PF(i, tt) { int tb_ = ((tt) << 6); \
    Q##i##kk = *(const float4*)&lds[cur][0][tb_ + kq]; \
    Q##i##ew = *(const float4*)&lds[cur][1][tb_ + kq]; \
    Q##i##k  = *(const float4*)&lds[cur][2][tb_ + kq]; \
    Q##i##bb = *(const float4*)&lds[cur][3][tb_ + kq]; \
    Q##i##r  = *(const float4*)&lds[cur][4][tb_ + kq]; \
    Q##i##v  = lds[cur][5][tb_ + row]; }
#define SBAR __builtin_amdgcn_sched_barrier(0x7)
#define ST(i, gtok) { \
    float p_ = fmaf(S1, Q##i##kk.y, S0 * Q##i##kk.x) + \
               fmaf(S3, Q##i##kk.w, S2 * Q##i##kk.z); \
    float sab = qsum16(p_); \
    float n0 = fmaf(S0, Q##i##ew.x, Q##i##v * Q##i##k.x); \
    float n1 = fmaf(S1, Q##i##ew.y, Q##i##v * Q##i##k.y); \
    float n2 = fmaf(S2, Q##i##ew.z, Q##i##v * Q##i##k.z); \
    float n3 = fmaf(S3, Q##i##ew.w, Q##i##v * Q##i##k.w); \
    S0 = fmaf(sab, Q##i##bb.x, n0); \
    S1 = fmaf(sab, Q##i##bb.y, n1); \
    S2 = fmaf(sab, Q##i##bb.z, n2); \
    S3 = fmaf(sab, Q##i##bb.w, n3); \
    float yp_ = fmaf(S1, Q##i##r.y, S0 * Q##i##r.x) + \
                fmaf(S3, Q##i##r.w, S2 * Q##i##r.z); \
    float yv_ = qsum16(yp_); \
    if (q == 0) yB[base + (long)(gtok) * C_ + row] = yv_; }

  // prologue: chunk 0 -> buf0; chunk 1 loaded into regs
  loadc(0);
  stage(0);
  loadc(1);
  __syncthreads();
  int cur = 0;
  for (int c = 0; c < NCHUNK; c++) {
    int t0 = c << 4;
    // prefetch tokens 0,1 of this chunk (reads queue before the stage writes)
    PF(0, 0); PF(1, 1);
    if (c + 1 < NCHUNK) stage(cur ^ 1);   // regs hold chunk c+1
    if (c + 2 < NCHUNK) loadc(c + 2);     // issue global loads, 16-token cover
    SBAR;
    PF(2, 2);  SBAR; ST(0, t0 + 0);
    PF(0, 3);  SBAR; ST(1, t0 + 1);
    PF(1, 4);  SBAR; ST(2, t0 + 2);
    PF(2, 5);  SBAR; ST(0, t0 + 3);
    PF(0, 6);  SBAR; ST(1, t0 + 4);
    PF(1, 7);  SBAR; ST(2, t0 + 5);
    PF(2, 8);  SBAR; ST(0, t0 + 6);
    PF(0, 9);  SBAR; ST(1, t0 + 7);
    PF(1, 10); SBAR; ST(2, t0 + 8);
    PF(2, 11); SBAR; ST(0, t0 + 9);
    PF(0, 12); SBAR; ST(1, t0 + 10);
    PF(1, 13); SBAR; ST(2, t0 + 11);
    PF(2, 14); SBAR; ST(0, t0 + 12);
    PF(0, 15); SBAR; ST(1, t0 + 13);
    ST(2, t0 + 14);
    ST(0, t0 + 15);
    __syncthreads();
    cur ^= 1;
  }
#undef PF
#undef SBAR
#undef ST
}

// ---------------- K7: GroupNorm + bonus + gate (bf16 out) -------------------
__global__ __launch_bounds__(256) void gnout_kernel(
    const float* __restrict__ y, const float* __restrict__ r,
    const float* __restrict__ kf, const float* __restrict__ v,
    const float* __restrict__ g,
    const float* __restrict__ lnw, const float* __restrict__ lnb,
    const float* __restrict__ fa, bf16* __restrict__ z) {
  int tid = threadIdx.x;
  int w = tid >> 6, lane = tid & 63;
  int gi = (blockIdx.x << 2) + w;  // (b*T+t)*H + h
  int h = gi & 15, mt = gi >> 4;
  long off = (long)mt * C_ + (h << 6) + lane;
  float yv = y[off];
  float s = yv;
  s += __shfl_xor(s, 1); s += __shfl_xor(s, 2); s += __shfl_xor(s, 4);
  s += __shfl_xor(s, 8); s += __shfl_xor(s, 16); s += __shfl_xor(s, 32);
  float mu = s * (1.0f / 64.0f);
  float d = yv - mu;
  float s2 = d * d;
  s2 += __shfl_xor(s2, 1); s2 += __shfl_xor(s2, 2); s2 += __shfl_xor(s2, 4);
  s2 += __shfl_xor(s2, 8); s2 += __shfl_xor(s2, 16); s2 += __shfl_xor(s2, 32);
  float var = s2 * (1.0f / 64.0f);
  int hc = (h << 6) + lane;
  float dot = r[off] * kf[off] * fa[hc];
  dot += __shfl_xor(dot, 1); dot += __shfl_xor(dot, 2); dot += __shfl_xor(dot, 4);
  dot += __shfl_xor(dot, 8); dot += __shfl_xor(dot, 16); dot += __shfl_xor(dot, 32);
  float yn = d * rsqrtf(var + 0.00064f) * lnw[hc] + lnb[hc];
  z[off] = f2bf((yn + dot * v[off]) * g[off]);
}

extern "C" void kernel_launch(void* const* d_in, const int* in_sizes, int n_in,
                              void* d_out, int out_size, void* d_ws, size_t ws_size,
                              hipStream_t stream) {
  const float* x = (const float*)d_in[0];
  const float* tmx = (const float*)d_in[1];
  const float* tmaa = (const float*)d_in[2];
  const float* tmw1 = (const float*)d_in[3];
  const float* tmw2 = (const float*)d_in[4];
  const float* tdec = (const float*)d_in[5];
  const float* tdw1 = (const float*)d_in[6];
  const float* tdw2 = (const float*)d_in[7];
  const float* taa5 = (const float*)d_in[8];
  const float* taw1 = (const float*)d_in[9];
  const float* taw2 = (const float*)d_in[10];
  const float* tkw1 = (const float*)d_in[11];
  const float* tkw2 = (const float*)d_in[12];
  const float* gw1 = (const float*)d_in[13];
  const float* gw2 = (const float*)d_in[14];
  const float* tmia = (const float*)d_in[15];
  const float* maw1 = (const float*)d_in[16];
  const float* maw2 = (const float*)d_in[17];
  const float* tmik = (const float*)d_in[18];
  const float* mkw1 = (const float*)d_in[19];
  const float* mkw2 = (const float*)d_in[20];
  const float* wrec = (const float*)d_in[21];
  const float* wkey = (const float*)d_in[22];
  const float* wval = (const float*)d_in[23];
  const float* wout = (const float*)d_in[24];
  const float* lnw = (const float*)d_in[25];
  const float* lnb = (const float*)d_in[26];
  const float* faaa = (const float*)d_in[27];

  const long MT = 2048, CC = 1024;
  char* base = (char*)d_ws;
  float* xx = (float*)base;    base += MT * CC * 4;   // also y
  bf16* xxxb = (bf16*)base;    base += MT * CC * 2;
  bf16* xrgb = (bf16*)base;    base += MT * CC * 2;   // ┐ kfin overlays (8MB)
  bf16* xwab = (bf16*)base;    base += MT * CC * 2;   // ┘
  bf16* xkb = (bf16*)base;     base += MT * CC * 2;   // ┐ kkn overlays (8MB)
  bf16* xvb = (bf16*)base;     base += MT * CC * 2;   // ┘
  float* rr = (float*)base;    base += MT * CC * 4;
  float* kraw = (float*)base;  base += MT * CC * 4;   // also ew
  float* vv = (float*)base;    base += MT * CC * 4;
  float* gg = (float*)base;    base += MT * CC * 4;
  float* bbo = (float*)base;   base += MT * CC * 4;
  float* mix = (float*)base;   base += MT * 128 * 4;
  bf16* g1b = (bf16*)base;     base += MT * 128 * 2;
  float* out1 = (float*)base;  base += MT * 32 * 4;   // [kk1|mk1]
  float* out2 = (float*)base;  base += MT * 96 * 4;   // [w1|a1|ma1]
  bf16* zb = (bf16*)base;      base += MT * CC * 2;
  bf16* tmw1b = (bf16*)base;   base += 128 * CC * 2;
  bf16* wrecb = (bf16*)base;   base += CC * CC * 2;
  bf16* gw1b = (bf16*)base;    base += 128 * CC * 2;
  bf16* gw2b = (bf16*)base;    base += CC * 128 * 2;
  bf16* wkeyb = (bf16*)base;   base += CC * CC * 2;
  bf16* wvalb = (bf16*)base;   base += CC * CC * 2;
  bf16* woutb = (bf16*)base;   base += CC * CC * 2;
  bf16* wskb = (bf16*)base;    base += 32 * CC * 2;
  bf16* wswab = (bf16*)base;   base += 96 * CC * 2;
  bf16* tmw2b = (bf16*)base;   base += 4 * CC * 32 * 2;
  bf16* tdw2b = (bf16*)base;   base += CC * 64 * 2;
  bf16* tkw2b = (bf16*)base;   base += CC * 16 * 2;
  bf16* taw2b = (bf16*)base;   base += CC * 16 * 2;
  bf16* maw2b = (bf16*)base;   base += CC * 16 * 2;
  bf16* mkw2b = (bf16*)base;   base += CC * 16 * 2;
  // aliases (dead-buffer reuse, verified non-overlapping in time):
  float* ew = kraw;            // fuse2 reads kraw then writes ew at same offs
  float* kfin = (float*)xrgb;  // xrg/xwa bf16 dead before fuse2
  float* kkn = (float*)xkb;    // xk/xv bf16 dead before fuse2
  float* y = xx;               // xx dead after mix4

  auto gemm_m = [&](const bf16* A, const bf16* W, float* Cf, bf16* Cb,
                    int M, int N, int K, int actN) {
    dim3 grid((N + 63) / 64, M / 64);
    gemm_mfma_kernel<<<grid, 256, 0, stream>>>(A, W, Cf, Cb, M, N, K, actN);
  };

  cvt_weights_kernel<<<4480, 256, 0, stream>>>(
      tmw1, wrec, gw1, gw2, wkey, wval, wout,
      tmw1b, wrecb, gw1b, gw2b, wkeyb, wvalb, woutb);
  cvt_small_kernel<<<128, 256, 0, stream>>>(tkw1, mkw1, tdw1, taw1, maw1,
                                            wskb, wswab);
  cvt_small2_kernel<<<256, 256, 0, stream>>>(tmw2, tdw2, tkw2, taw2, maw2, mkw2,
                                             tmw2b, tdw2b, tkw2b, taw2b,
                                             maw2b, mkw2b);
  shift_kernel<<<8192, 256, 0, stream>>>(x, tmx, xx, xxxb);
  gemm_m(xxxb, tmw1b, mix, nullptr, 2048, 128, 1024, 128);   // tanh all
  mix4_kernel<<<2048, 256, 0, stream>>>(x, xx, mix, tmaa, tmw2b,
                                        xrgb, xwab, xkb, xvb);
  gemm_m(xrgb, wrecb, rr, nullptr, 2048, 1024, 1024, 0);
  gemm_m(xrgb, gw1b, nullptr, g1b, 2048, 128, 1024, 128);    // tanh all
  gemm_m(g1b, gw2b, gg, nullptr, 2048, 1024, 128, 0);
  gemm_m(xkb, wkeyb, kraw, nullptr, 2048, 1024, 1024, 0);
  gemm_m(xkb, wskb, out1, nullptr, 2048, 32, 1024, 16);      // tanh cols<16
  gemm_m(xvb, wvalb, vv, nullptr, 2048, 1024, 1024, 0);
  gemm_m(xwab, wswab, out2, nullptr, 2048, 96, 1024, 64);    // tanh cols<64
  fuse2_kernel<<<2048, 256, 0, stream>>>(kraw, out1, out2,
                                         tdw2b, tkw2b, taw2b, maw2b, mkw2b,
                                         tdec, taa5, tmia, tmik,
                                         ew, kfin, kkn, bbo);
  scan_kernel<<<128, 256, 0, stream>>>(rr, ew, kfin, vv, kkn, bbo, y);
  gnout_kernel<<<8192, 256, 0, stream>>>(y, rr, kfin, vv, gg, lnw, lnb, faaa, zb);
  gemm_m(zb, woutb, (float*)d_out, nullptr, 2048, 1024, 1024, 0);
}